// Round 7
// baseline (370.675 us; speedup 1.0000x reference)
//
#include <hip/hip_runtime.h>

#define BB 8
#define SS 4096
#define DD 768
#define NN 64
#define D4 (DD / 4)        // 192 float4 columns
#define CHT 128            // tokens per chunk
#define MAXCH 96           // max chunks per batch: 64 + 4032/128 = 95 <= 96
#define NREC (BB * MAXCH)  // 768 chunk records
#define SUM_BYTES ((size_t)NREC * DD * 4)      // 2,359,296
#define CNT_BYTES ((size_t)NREC * DD)          //   589,824
#define CTR_OFF   (SUM_BYTES + CNT_BYTES)      // 2,949,120 (4-aligned)
#define CTR_BYTES (BB * NN * 4)                //     2,048
// ws: float sum[NREC][DD] | u8 cnt[NREC][DD] | int ctr[BB*NN] (memset 0).
//
// R19 EXPERIMENT (finalize-dispatch theory): R17 calibration bounds the
// per-dispatch gap at <=6.4us, so under the period-3 dispatch model
// [chunk, finalize, fill(59.3)] the pair chunk+finalize ~= 90us while
// chunk <= 59.4 (absent from top-5) -> finalize + kernel-boundary overhead
// carries >=30us vs ~4us structural cost. Fix: eliminate the finalize
// dispatch. Last-arrival-per-segment pattern: record write -> syncthreads
// (drains vmcnt) -> tid0 threadfence(release) + device atomicAdd on
// ctr[b,n] -> 3K-th block threadfence(acquire) + inline finalize (all
// scan state already in registers). 2KB hipMemsetAsync zeroes counters.
// Streaming loop byte-identical to proven R15.
// Dead theories (do not retry): access pattern (R11), LDS-DMA (R12),
// plain/cached loads (R13, +9us), atomics-per-element windows (R14, +20us),
// DRAM-row co-scheduling (R15, neutral, kept), fewer/persistent blocks
// (R16, +22us), occupancy cap 256x8 (R18, neutral). Calibration: pure
// NT reader probe = 22.4us incl gap (R17).

// native vector type accepted by __builtin_nontemporal_load (float4 is a
// HIP_vector_type class, which the builtin rejects; this is layout-identical)
typedef float nfloat4 __attribute__((ext_vector_type(4)));

__global__ __launch_bounds__(256) void fused_kernel(
    const float* __restrict__ wv,
    const int* __restrict__ rep_ids,
    const float* __restrict__ rep_mask,
    const int* __restrict__ lens,
    const float* __restrict__ len_mask,
    float* __restrict__ ws_sum,
    unsigned char* __restrict__ ws_cnt,
    int* __restrict__ ctr,
    float* __restrict__ out)
{
    const int cidx = blockIdx.x / 3;  // chunk slot within batch
    const int g    = blockIdx.x % 3;  // colgroup 0..2 (fastest -> co-scheduled)
    const int b    = blockIdx.y;
    const int tid  = threadIdx.x;
    const int lane = tid & 63;
    const int w    = tid >> 6;       // 0..3

    // per-wave redundant scans over the 64 segment lengths
    const int l    = lens[b * NN + lane];
    const int nchl = (l + CHT - 1) >> 7;      // chunks in this segment
    int inclen = l, inch = nchl;
    #pragma unroll
    for (int off = 1; off < 64; off <<= 1) {
        int a = __shfl_up(inclen, off); if (lane >= off) inclen += a;
        int c = __shfl_up(inch,   off); if (lane >= off) inch   += c;
    }
    const int total_ch = __shfl(inch, 63);
    if (cidx >= total_ch) return;             // uniform: whole block exits

    // owning segment: first n with inclusive chunk-scan > cidx
    unsigned long long m = __ballot(inch > cidx);
    const int n         = __ffsll(m) - 1;
    const int seg_len   = __shfl(l, n);
    const int seg_start = __shfl(inclen, n) - seg_len;
    const int K         = __shfl(nchl, n);           // chunks in this segment
    const int ch_base   = __shfl(inch, n) - K;
    const int t0 = seg_start + (cidx - ch_base) * CHT;
    const int t1 = min(seg_start + seg_len, t0 + CHT);

    const int col4 = g * 64 + lane;
    const nfloat4* base = (const nfloat4*)wv + (size_t)b * SS * D4 + col4;

    float4 s = make_float4(0.f, 0.f, 0.f, 0.f);
    float4 c = make_float4(0.f, 0.f, 0.f, 0.f);
    #pragma unroll 8
    for (int t = t0 + w; t < t1; t += 4) {
        nfloat4 v = __builtin_nontemporal_load(base + (size_t)t * D4);
        s.x += v.x; s.y += v.y; s.z += v.z; s.w += v.w;
        c.x += (v.x != 0.f) ? 1.f : 0.f;
        c.y += (v.y != 0.f) ? 1.f : 0.f;
        c.z += (v.z != 0.f) ? 1.f : 0.f;
        c.w += (v.w != 0.f) ? 1.f : 0.f;
    }

    __shared__ float4 s_s[4][64];
    __shared__ float4 s_c[4][64];
    __shared__ float s_part[4];
    __shared__ int s_last;
    s_s[w][lane] = s;
    s_c[w][lane] = c;
    __syncthreads();

    if (tid < 64) {
        float4 S = make_float4(0.f, 0.f, 0.f, 0.f);
        float4 C = make_float4(0.f, 0.f, 0.f, 0.f);
        #pragma unroll
        for (int j = 0; j < 4; ++j) {
            float4 a = s_s[j][tid], d = s_c[j][tid];
            S.x += a.x; S.y += a.y; S.z += a.z; S.w += a.w;
            C.x += d.x; C.y += d.y; C.z += d.z; C.w += d.w;
        }
        const size_t rec = (size_t)(b * MAXCH + cidx);
        ((float4*)ws_sum)[rec * D4 + g * 64 + tid] = S;
        uchar4 u;                      // chunk counts <= 128, exact in u8
        u.x = (unsigned char)C.x; u.y = (unsigned char)C.y;
        u.z = (unsigned char)C.z; u.w = (unsigned char)C.w;
        ((uchar4*)ws_cnt)[rec * D4 + g * 64 + tid] = u;
    }

    // ---- last-arrival detection (canonical pattern) ----
    // __syncthreads drains vmcnt for ALL threads' record stores (compiler
    // emits s_waitcnt vmcnt(0) before s_barrier), so tid0's fence releases
    // the whole block's writes.
    __syncthreads();
    if (tid == 0) {
        __threadfence();                         // release: wbl2, agent scope
        int old = atomicAdd(&ctr[b * NN + n], 1); // device-scope (m20)
        s_last = (old == 3 * K - 1);
    }
    __syncthreads();
    if (!s_last) return;

    __threadfence();   // acquire: invalidate L1/L2 so record reads are fresh

    // ---- inline finalize for segment (b, n): proven epilogue ----
    const int sgid = b * NN + n;
    const bool active = tid < D4;

    float4 S = make_float4(0,0,0,0), C = S;
    if (active) {
        for (int k = 0; k < K; ++k) {
            const size_t rec = (size_t)(b * MAXCH + ch_base + k);
            float4 sv = ((const float4*)ws_sum)[rec * D4 + tid];
            uchar4 cv = ((const uchar4*)ws_cnt)[rec * D4 + tid];
            S.x += sv.x; S.y += sv.y; S.z += sv.z; S.w += sv.w;
            C.x += (float)cv.x; C.y += (float)cv.y;
            C.z += (float)cv.z; C.w += (float)cv.w;
        }
    }

    float tot = C.x + C.y + C.z + C.w;    // 0 for inactive lanes
    #pragma unroll
    for (int off = 32; off; off >>= 1) tot += __shfl_xor(tot, off);
    if ((tid & 63) == 0) s_part[tid >> 6] = tot;
    __syncthreads();
    const float total = s_part[0] + s_part[1] + s_part[2] + s_part[3];

    if (active) {
        float4 mean;
        mean.x = S.x / fmaxf(C.x, 1.f);
        mean.y = S.y / fmaxf(C.y, 1.f);
        mean.z = S.z / fmaxf(C.z, 1.f);
        mean.w = S.w / fmaxf(C.w, 1.f);
        if (total == 0.f) mean = ((const float4*)wv)[tid];   // wv[0,0,:]

        const float lm = len_mask[sgid];
        mean.x *= lm; mean.y *= lm; mean.z *= lm; mean.w *= lm;

        float4* out4 = (float4*)out;
        out4[(size_t)(b * 2 * NN + NN + n) * D4 + tid] = mean;

        const int   rid = rep_ids[sgid];
        const float rm  = rep_mask[sgid];
        float4 rv = ((const float4*)wv)[(size_t)(b * SS + rid) * D4 + tid];
        rv.x *= rm; rv.y *= rm; rv.z *= rm; rv.w *= rm;
        out4[(size_t)(b * 2 * NN + n) * D4 + tid] = rv;

        if (tid == 0) {
            float* masks = out + (size_t)BB * 2 * NN * DD;
            masks[b * 2 * NN + n]      = rm;
            masks[b * 2 * NN + NN + n] = lm;
        }
    }
}

extern "C" void kernel_launch(void* const* d_in, const int* in_sizes, int n_in,
                              void* d_out, int out_size, void* d_ws, size_t ws_size,
                              hipStream_t stream) {
    const float* wv       = (const float*)d_in[0];
    const int*   rep_ids  = (const int*)d_in[1];
    const float* rep_mask = (const float*)d_in[2];
    const int*   lens     = (const int*)d_in[3];
    const float* len_mask = (const float*)d_in[4];
    float*       out      = (float*)d_out;
    float*         ws_sum = (float*)d_ws;
    unsigned char* ws_cnt = (unsigned char*)d_ws + SUM_BYTES;
    int*           ctr    = (int*)((char*)d_ws + CTR_OFF);

    hipMemsetAsync(ctr, 0, CTR_BYTES, stream);   // graph-capturable memset node
    fused_kernel<<<dim3(3 * MAXCH, BB), 256, 0, stream>>>(
        wv, rep_ids, rep_mask, lens, len_mask, ws_sum, ws_cnt, ctr, out);
}

// Round 8
// 249.430 us; speedup vs baseline: 1.4861x; 1.4861x over previous
//
#include <hip/hip_runtime.h>

#define BB 8
#define SS 4096
#define DD 768
#define NN 64
#define D4 (DD / 4)        // 192 float4 columns
#define CHT 128            // tokens per chunk
#define MAXCH 96           // max chunks per batch: 64 + 4032/128 = 95 <= 96
#define NREC (BB * MAXCH)  // 768 chunk records
#define FREP 16            // finalize internal repeat (measurement round)
// ws layout: float sum[NREC][DD] (2,359,296 B) then u8 cnt[NREC][DD] (589,824 B)
//
// R20 MEASUREMENT ROUND (deliberate dur sacrifice): 7 rounds of structural
// theories refuted; the chunk/finalize/gap split of the ~96us controllable
// budget has never been measured (top-5 always fills). This round: proven
// R15 pipeline, but chunk launched 4x (idempotent; dispatches 2-4 run with
// wv L3-warm -> cold-vs-warm delta isolates HBM-fetch share) and finalize
// runs a laundered x16 internal repeat (surfaces its true cost + counters).
// Top-5 = {finalize_x16, chunk x4} with full PMC.
// R19 lesson: per-block __threadfence on 8-XCD = memory-system serialization
// (310us, hbm 17 GB/s) — device-fence-per-block is DEAD. R19 bonus: fused
// FETCH=51MB for a 100MB stream -> wv is partially L3-resident across
// iterations; in-flight-bytes math: a wave dwordx4 = 1KB -> MLP was never
// the limit (R18's theory retracted).
// Dead theories: access pattern (R11), LDS-DMA (R12), plain loads (R13),
// atomics windows (R14), DRAM co-scheduling (R15, neutral), fewer blocks
// (R16), occupancy cap (R18), per-block fences (R19).

// native vector type accepted by __builtin_nontemporal_load (float4 is a
// HIP_vector_type class, which the builtin rejects; this is layout-identical)
typedef float nfloat4 __attribute__((ext_vector_type(4)));

// ---------------- Phase B: chunk partials (proven R15, UNCHANGED) ----------
__global__ __launch_bounds__(256) void chunk_kernel(
    const float* __restrict__ wv,
    const int* __restrict__ lens,
    float* __restrict__ ws_sum,
    unsigned char* __restrict__ ws_cnt)
{
    const int cidx = blockIdx.x / 3;  // chunk slot within batch
    const int g    = blockIdx.x % 3;  // colgroup 0..2 (fastest -> co-scheduled)
    const int b    = blockIdx.y;
    const int tid  = threadIdx.x;
    const int lane = tid & 63;
    const int w    = tid >> 6;       // 0..3

    const int l    = lens[b * NN + lane];
    const int nchl = (l + CHT - 1) >> 7;      // chunks in this segment
    int inclen = l, inch = nchl;
    #pragma unroll
    for (int off = 1; off < 64; off <<= 1) {
        int a = __shfl_up(inclen, off); if (lane >= off) inclen += a;
        int c = __shfl_up(inch,   off); if (lane >= off) inch   += c;
    }
    const int total_ch = __shfl(inch, 63);
    if (cidx >= total_ch) return;             // uniform: whole block exits

    unsigned long long m = __ballot(inch > cidx);
    const int n         = __ffsll(m) - 1;
    const int seg_len   = __shfl(l, n);
    const int seg_start = __shfl(inclen, n) - seg_len;
    const int ch_base   = __shfl(inch, n) - __shfl(nchl, n);
    const int t0 = seg_start + (cidx - ch_base) * CHT;
    const int t1 = min(seg_start + seg_len, t0 + CHT);

    const int col4 = g * 64 + lane;
    const nfloat4* base = (const nfloat4*)wv + (size_t)b * SS * D4 + col4;

    float4 s = make_float4(0.f, 0.f, 0.f, 0.f);
    float4 c = make_float4(0.f, 0.f, 0.f, 0.f);
    #pragma unroll 8
    for (int t = t0 + w; t < t1; t += 4) {
        nfloat4 v = __builtin_nontemporal_load(base + (size_t)t * D4);
        s.x += v.x; s.y += v.y; s.z += v.z; s.w += v.w;
        c.x += (v.x != 0.f) ? 1.f : 0.f;
        c.y += (v.y != 0.f) ? 1.f : 0.f;
        c.z += (v.z != 0.f) ? 1.f : 0.f;
        c.w += (v.w != 0.f) ? 1.f : 0.f;
    }

    __shared__ float4 s_s[4][64];
    __shared__ float4 s_c[4][64];
    s_s[w][lane] = s;
    s_c[w][lane] = c;
    __syncthreads();

    if (tid < 64) {
        float4 S = make_float4(0.f, 0.f, 0.f, 0.f);
        float4 C = make_float4(0.f, 0.f, 0.f, 0.f);
        #pragma unroll
        for (int j = 0; j < 4; ++j) {
            float4 a = s_s[j][tid], d = s_c[j][tid];
            S.x += a.x; S.y += a.y; S.z += a.z; S.w += a.w;
            C.x += d.x; C.y += d.y; C.z += d.z; C.w += d.w;
        }
        const size_t rec = (size_t)(b * MAXCH + cidx);
        ((float4*)ws_sum)[rec * D4 + g * 64 + tid] = S;
        uchar4 u;                      // chunk counts <= 128, exact in u8
        u.x = (unsigned char)C.x; u.y = (unsigned char)C.y;
        u.z = (unsigned char)C.z; u.w = (unsigned char)C.w;
        ((uchar4*)ws_cnt)[rec * D4 + g * 64 + tid] = u;
    }
}

// ---------------- Phase C: finalize with x16 laundered repeat --------------
__global__ __launch_bounds__(256) void finalize_kernel(
    const float* __restrict__ wv,
    const int* __restrict__ rep_ids,
    const float* __restrict__ rep_mask,
    const int* __restrict__ lens,
    const float* __restrict__ len_mask,
    const float* __restrict__ ws_sum,
    const unsigned char* __restrict__ ws_cnt,
    float* __restrict__ out)
{
    __shared__ float s_part[4];
    __shared__ int s_info[2];
    const int sgid = blockIdx.x;          // b*NN + n
    const int b = sgid >> 6, n = sgid & 63;
    const int tid = threadIdx.x;
    const int lane = tid & 63;

    if (tid < 64) {                       // wave 0: chunk-base scan
        const int l    = lens[b * NN + tid];
        const int nchl = (l + CHT - 1) >> 7;
        int inch = nchl;
        #pragma unroll
        for (int off = 1; off < 64; off <<= 1) {
            int a = __shfl_up(inch, off); if (lane >= off) inch += a;
        }
        if (tid == n) { s_info[0] = inch - nchl; s_info[1] = nchl; }
    }
    __syncthreads();
    const int ch_base = s_info[0];
    const int K       = s_info[1];
    const bool active = tid < D4;

    for (int rep = 0; rep < FREP; ++rep) {
        // launder pointers so each repeat re-executes the full memory work
        const float* vs = ws_sum;
        const unsigned char* vc = ws_cnt;
        const float* vw = wv;
        asm volatile("" : "+v"(vs), "+v"(vc), "+v"(vw));

        float4 S = make_float4(0,0,0,0), C = S;
        if (active) {
            for (int k = 0; k < K; ++k) {
                const size_t rec = (size_t)(b * MAXCH + ch_base + k);
                float4 sv = ((const float4*)vs)[rec * D4 + tid];
                uchar4 cv = ((const uchar4*)vc)[rec * D4 + tid];
                S.x += sv.x; S.y += sv.y; S.z += sv.z; S.w += sv.w;
                C.x += (float)cv.x; C.y += (float)cv.y;
                C.z += (float)cv.z; C.w += (float)cv.w;
            }
        }

        float tot = C.x + C.y + C.z + C.w;    // 0 for inactive lanes
        #pragma unroll
        for (int off = 32; off; off >>= 1) tot += __shfl_xor(tot, off);
        if ((tid & 63) == 0) s_part[tid >> 6] = tot;
        __syncthreads();
        const float total = s_part[0] + s_part[1] + s_part[2] + s_part[3];

        if (active) {
            float4 mean;
            mean.x = S.x / fmaxf(C.x, 1.f);
            mean.y = S.y / fmaxf(C.y, 1.f);
            mean.z = S.z / fmaxf(C.z, 1.f);
            mean.w = S.w / fmaxf(C.w, 1.f);
            if (total == 0.f) mean = ((const float4*)vw)[tid];   // wv[0,0,:]

            const float lm = len_mask[sgid];
            mean.x *= lm; mean.y *= lm; mean.z *= lm; mean.w *= lm;

            float4* out4 = (float4*)out;
            out4[(size_t)(b * 2 * NN + NN + n) * D4 + tid] = mean;

            const int   rid = rep_ids[sgid];
            const float rm  = rep_mask[sgid];
            float4 rv = ((const float4*)vw)[(size_t)(b * SS + rid) * D4 + tid];
            rv.x *= rm; rv.y *= rm; rv.z *= rm; rv.w *= rm;
            out4[(size_t)(b * 2 * NN + n) * D4 + tid] = rv;

            if (tid == 0) {
                float* masks = out + (size_t)BB * 2 * NN * DD;
                masks[b * 2 * NN + n]      = rm;
                masks[b * 2 * NN + NN + n] = lm;
            }
        }
        __syncthreads();   // s_part reuse across repeats
    }
}

extern "C" void kernel_launch(void* const* d_in, const int* in_sizes, int n_in,
                              void* d_out, int out_size, void* d_ws, size_t ws_size,
                              hipStream_t stream) {
    const float* wv       = (const float*)d_in[0];
    const int*   rep_ids  = (const int*)d_in[1];
    const float* rep_mask = (const float*)d_in[2];
    const int*   lens     = (const int*)d_in[3];
    const float* len_mask = (const float*)d_in[4];
    float*       out      = (float*)d_out;
    float*         ws_sum = (float*)d_ws;
    unsigned char* ws_cnt = (unsigned char*)d_ws + (size_t)NREC * DD * 4;

    dim3 gridB(3 * MAXCH, BB);
    // 4 idempotent chunk launches: #1 cold, #2-4 wv-L3-warm -> per-dispatch
    // counters split fetch-bound vs execution-bound time.
    chunk_kernel<<<gridB, 256, 0, stream>>>(wv, lens, ws_sum, ws_cnt);
    chunk_kernel<<<gridB, 256, 0, stream>>>(wv, lens, ws_sum, ws_cnt);
    chunk_kernel<<<gridB, 256, 0, stream>>>(wv, lens, ws_sum, ws_cnt);
    chunk_kernel<<<gridB, 256, 0, stream>>>(wv, lens, ws_sum, ws_cnt);
    finalize_kernel<<<BB * NN, 256, 0, stream>>>(wv, rep_ids, rep_mask, lens,
                                                 len_mask, ws_sum, ws_cnt, out);
}

// Round 9
// 161.132 us; speedup vs baseline: 2.3004x; 1.5480x over previous
//
#include <hip/hip_runtime.h>

#define BB 8
#define SS 4096
#define DD 768
#define NN 64
#define D4 (DD / 4)        // 192 float4 columns
#define CHT 128            // tokens per chunk
#define MAXCH 96           // max chunks per batch: 64 + 4032/128 = 95 <= 96
#define NREC (BB * MAXCH)  // 768 chunk records
#define SUMW_BYTES ((size_t)NREC * 4 * DD * 4)   // 9,437,184 B (4 waves/rec)
// ws layout: float sum[NREC][4][DD] (9.44 MB) then u8 cnt[NREC][4][DD]
// (2.36 MB). Total ~11.8 MB << ws (the harness poisons ~400 MB of ws).
// No zero-init: every sub-record read by finalize is written by exactly one
// owner wave.
//
// R21 EXPERIMENT (block-tail theory): R20+R17 calibration closed the budget:
// fixed harness/iter ~121us (wv restore-copy ~58 + ws poison-fill ~59.3 +
// gaps), finalize < 3.7us (x16 repeat absent from top-5), chunk_cold ~25-29
// vs pure-probe 21-22 (R17, identical pattern/prologue, no counts/LDS/
// records). Count VALU arithmetic ~1us -> the 4-7us chunk-vs-probe delta is
// the LDS reduce + wave0-only record tail (syncthreads parks 3 waves, wave0
// serially reduces 4KB + writes; delays block retirement; ~9 blocks/CU
// serialize it). Fix: per-WAVE records — each wave stores its own partial
// (no __shared__, no __syncthreads, no tail); finalize sums 4 sub-records
// per chunk (avg K=1.43 -> ~5.7 reads/thread, +~1us).
// Dead theories (do not retry): access pattern (R11), LDS-DMA (R12), plain
// loads (R13, +9), atomics windows (R14, +21), DRAM co-scheduling (R15,
// neutral), fewer/persistent blocks (R16, +22 — residency matters), occupancy
// cap (R18, neutral — was not VGPR-tiered), per-block device fences (R19,
// +215, memory-system serialization on 8 XCDs).

// native vector type accepted by __builtin_nontemporal_load (float4 is a
// HIP_vector_type class, which the builtin rejects; this is layout-identical)
typedef float nfloat4 __attribute__((ext_vector_type(4)));

// ---------------- Phase B: per-wave chunk partials, no LDS, no sync --------
// grid: (3*MAXCH, BB), block 256 (4 waves). Block (x=cidx*3+g, b) locates its
// chunk (<=128 tokens, wholly inside one segment) via wave scans, streams
// tokens stride-4-waves reading float4 col g*64+lane with NON-TEMPORAL loads,
// then each wave writes its own 64-col sub-record (coalesced 1KB + 256B).
__global__ __launch_bounds__(256) void chunk_kernel(
    const float* __restrict__ wv,
    const int* __restrict__ lens,
    float* __restrict__ ws_sum,
    unsigned char* __restrict__ ws_cnt)
{
    const int cidx = blockIdx.x / 3;  // chunk slot within batch
    const int g    = blockIdx.x % 3;  // colgroup 0..2 (fastest -> co-scheduled)
    const int b    = blockIdx.y;
    const int tid  = threadIdx.x;
    const int lane = tid & 63;
    const int w    = tid >> 6;       // 0..3

    // per-wave redundant scans over the 64 segment lengths
    const int l    = lens[b * NN + lane];
    const int nchl = (l + CHT - 1) >> 7;      // chunks in this segment
    int inclen = l, inch = nchl;
    #pragma unroll
    for (int off = 1; off < 64; off <<= 1) {
        int a = __shfl_up(inclen, off); if (lane >= off) inclen += a;
        int c = __shfl_up(inch,   off); if (lane >= off) inch   += c;
    }
    const int total_ch = __shfl(inch, 63);
    if (cidx >= total_ch) return;             // uniform: whole block exits

    // owning segment: first n with inclusive chunk-scan > cidx
    unsigned long long m = __ballot(inch > cidx);
    const int n         = __ffsll(m) - 1;
    const int seg_len   = __shfl(l, n);
    const int seg_start = __shfl(inclen, n) - seg_len;
    const int ch_base   = __shfl(inch, n) - __shfl(nchl, n);
    const int t0 = seg_start + (cidx - ch_base) * CHT;
    const int t1 = min(seg_start + seg_len, t0 + CHT);

    const int col4 = g * 64 + lane;
    const nfloat4* base = (const nfloat4*)wv + (size_t)b * SS * D4 + col4;

    float4 s = make_float4(0.f, 0.f, 0.f, 0.f);
    float4 c = make_float4(0.f, 0.f, 0.f, 0.f);
    #pragma unroll 8
    for (int t = t0 + w; t < t1; t += 4) {
        nfloat4 v = __builtin_nontemporal_load(base + (size_t)t * D4);
        s.x += v.x; s.y += v.y; s.z += v.z; s.w += v.w;
        c.x += (v.x != 0.f) ? 1.f : 0.f;
        c.y += (v.y != 0.f) ? 1.f : 0.f;
        c.z += (v.z != 0.f) ? 1.f : 0.f;
        c.w += (v.w != 0.f) ? 1.f : 0.f;
    }

    // per-wave sub-record: no LDS round-trip, no barrier, block retires
    // as soon as stores issue. Per-wave counts <= ceil(128/4)=32, exact u8.
    const size_t rec4 = (size_t)(b * MAXCH + cidx) * 4 + w;
    ((float4*)ws_sum)[rec4 * D4 + col4] = s;
    uchar4 u;
    u.x = (unsigned char)c.x; u.y = (unsigned char)c.y;
    u.z = (unsigned char)c.z; u.w = (unsigned char)c.w;
    ((uchar4*)ws_cnt)[rec4 * D4 + col4] = u;
}

// ---------------- Phase C: finalize (mean, fallback, rep, masks) -----------
// grid: BB*NN = 512 blocks, 256 threads (192 active cols). Gathers the
// segment's K chunks x 4 wave sub-records, then proven epilogue.
__global__ __launch_bounds__(256) void finalize_kernel(
    const float* __restrict__ wv,
    const int* __restrict__ rep_ids,
    const float* __restrict__ rep_mask,
    const int* __restrict__ lens,
    const float* __restrict__ len_mask,
    const float* __restrict__ ws_sum,
    const unsigned char* __restrict__ ws_cnt,
    float* __restrict__ out)
{
    __shared__ float s_part[4];
    __shared__ int s_info[2];
    const int sgid = blockIdx.x;          // b*NN + n
    const int b = sgid >> 6, n = sgid & 63;
    const int tid = threadIdx.x;
    const int lane = tid & 63;

    if (tid < 64) {                       // wave 0: chunk-base scan
        const int l    = lens[b * NN + tid];
        const int nchl = (l + CHT - 1) >> 7;
        int inch = nchl;
        #pragma unroll
        for (int off = 1; off < 64; off <<= 1) {
            int a = __shfl_up(inch, off); if (lane >= off) inch += a;
        }
        if (tid == n) { s_info[0] = inch - nchl; s_info[1] = nchl; }
    }
    __syncthreads();
    const int ch_base = s_info[0];
    const int K       = s_info[1];
    const bool active = tid < D4;

    float4 S = make_float4(0,0,0,0), C = S;
    if (active) {
        const size_t r0 = (size_t)(b * MAXCH + ch_base) * 4;
        for (int j = 0; j < 4 * K; ++j) {          // K chunks x 4 waves
            float4 sv = ((const float4*)ws_sum)[(r0 + j) * D4 + tid];
            uchar4 cv = ((const uchar4*)ws_cnt)[(r0 + j) * D4 + tid];
            S.x += sv.x; S.y += sv.y; S.z += sv.z; S.w += sv.w;
            C.x += (float)cv.x; C.y += (float)cv.y;
            C.z += (float)cv.z; C.w += (float)cv.w;
        }
    }

    float tot = C.x + C.y + C.z + C.w;    // 0 for inactive lanes
    #pragma unroll
    for (int off = 32; off; off >>= 1) tot += __shfl_xor(tot, off);
    if ((tid & 63) == 0) s_part[tid >> 6] = tot;
    __syncthreads();
    const float total = s_part[0] + s_part[1] + s_part[2] + s_part[3];

    if (active) {
        float4 mean;
        mean.x = S.x / fmaxf(C.x, 1.f);
        mean.y = S.y / fmaxf(C.y, 1.f);
        mean.z = S.z / fmaxf(C.z, 1.f);
        mean.w = S.w / fmaxf(C.w, 1.f);
        if (total == 0.f) mean = ((const float4*)wv)[tid];   // wv[0,0,:]

        const float lm = len_mask[sgid];
        mean.x *= lm; mean.y *= lm; mean.z *= lm; mean.w *= lm;

        float4* out4 = (float4*)out;
        out4[(size_t)(b * 2 * NN + NN + n) * D4 + tid] = mean;

        const int   rid = rep_ids[sgid];
        const float rm  = rep_mask[sgid];
        float4 rv = ((const float4*)wv)[(size_t)(b * SS + rid) * D4 + tid];
        rv.x *= rm; rv.y *= rm; rv.z *= rm; rv.w *= rm;
        out4[(size_t)(b * 2 * NN + n) * D4 + tid] = rv;

        if (tid == 0) {
            float* masks = out + (size_t)BB * 2 * NN * DD;
            masks[b * 2 * NN + n]      = rm;
            masks[b * 2 * NN + NN + n] = lm;
        }
    }
}

extern "C" void kernel_launch(void* const* d_in, const int* in_sizes, int n_in,
                              void* d_out, int out_size, void* d_ws, size_t ws_size,
                              hipStream_t stream) {
    const float* wv       = (const float*)d_in[0];
    const int*   rep_ids  = (const int*)d_in[1];
    const float* rep_mask = (const float*)d_in[2];
    const int*   lens     = (const int*)d_in[3];
    const float* len_mask = (const float*)d_in[4];
    float*       out      = (float*)d_out;
    float*         ws_sum = (float*)d_ws;
    unsigned char* ws_cnt = (unsigned char*)d_ws + SUMW_BYTES;

    dim3 gridB(3 * MAXCH, BB);
    chunk_kernel<<<gridB, 256, 0, stream>>>(wv, lens, ws_sum, ws_cnt);
    finalize_kernel<<<BB * NN, 256, 0, stream>>>(wv, rep_ids, rep_mask, lens,
                                                 len_mask, ws_sum, ws_cnt, out);
}

// Round 10
// 157.903 us; speedup vs baseline: 2.3475x; 1.0204x over previous
//
#include <hip/hip_runtime.h>

#define BB 8
#define SS 4096
#define DD 768
#define NN 64
#define D4 (DD / 4)        // 192 float4 columns
#define CHT 128            // tokens per chunk
#define MAXCH 96           // max chunks per batch: 64 + 4032/128 = 95 <= 96
#define NREC (BB * MAXCH)  // 768 chunk records
// ws layout: float sum[NREC][DD] (2,359,296 B) then u8 cnt[NREC][DD] (589,824 B)
// total 2,949,120 B <= ws_size. No zero-init: every record read by finalize
// is written by exactly one owner block.
//
// R22 FINAL: revert to the best-measured configuration (R15, 155.8us).
// Closed budget, all terms measured over R17/R18/R20 calibration rounds:
//   ~121us harness-fixed/iter = wv restore copyBuffer ~58-61 (R18 top-5,
//     WRITE=98304KB=wv) + ws poison fill 59.3 (every top-5) + gaps;
//   chunk ~25-29us vs identical-pattern pure-reader floor 21-22us (R17);
//   finalize < 3.7us (R20 x16 repeat absent from top-5); gap <= 6.4us.
// Nine structural reader variants all neutral-or-worse:
//   R11 pattern, R12 LDS-DMA, R13 cached loads (+9), R14 atomic windows
//   (+21), R15 DRAM co-scheduling (0, kept), R16 persistent blocks (+22),
//   R18 occupancy cap (0), R19 per-block fences (+215), R21 per-wave
//   records (+5). Demand-read ~4.5 TB/s is this op's empirical floor;
//   remaining slack < noise band (+-3us).

// native vector type accepted by __builtin_nontemporal_load (float4 is a
// HIP_vector_type class, which the builtin rejects; this is layout-identical)
typedef float nfloat4 __attribute__((ext_vector_type(4)));

// ---------------- Phase B: balanced chunk partials, NO atomics --------------
// grid: (3*MAXCH, BB), block 256 (4 waves). Block (x=cidx*3+g, b) locates its
// chunk (<=128 tokens, wholly inside one segment) via wave scans, streams
// tokens stride-4-waves reading float4 col g*64+lane with NON-TEMPORAL loads,
// LDS-reduces, writes its 64-col record slice with plain stores.
__global__ __launch_bounds__(256) void chunk_kernel(
    const float* __restrict__ wv,
    const int* __restrict__ lens,
    float* __restrict__ ws_sum,
    unsigned char* __restrict__ ws_cnt)
{
    const int cidx = blockIdx.x / 3;  // chunk slot within batch
    const int g    = blockIdx.x % 3;  // colgroup 0..2 (fastest -> co-scheduled)
    const int b    = blockIdx.y;
    const int tid  = threadIdx.x;
    const int lane = tid & 63;
    const int w    = tid >> 6;       // 0..3

    // per-wave redundant scans over the 64 segment lengths
    const int l    = lens[b * NN + lane];
    const int nchl = (l + CHT - 1) >> 7;      // chunks in this segment
    int inclen = l, inch = nchl;
    #pragma unroll
    for (int off = 1; off < 64; off <<= 1) {
        int a = __shfl_up(inclen, off); if (lane >= off) inclen += a;
        int c = __shfl_up(inch,   off); if (lane >= off) inch   += c;
    }
    const int total_ch = __shfl(inch, 63);
    if (cidx >= total_ch) return;             // uniform: whole block exits

    // owning segment: first n with inclusive chunk-scan > cidx
    unsigned long long m = __ballot(inch > cidx);
    const int n         = __ffsll(m) - 1;
    const int seg_len   = __shfl(l, n);
    const int seg_start = __shfl(inclen, n) - seg_len;
    const int ch_base   = __shfl(inch, n) - __shfl(nchl, n);
    const int t0 = seg_start + (cidx - ch_base) * CHT;
    const int t1 = min(seg_start + seg_len, t0 + CHT);

    const int col4 = g * 64 + lane;
    const nfloat4* base = (const nfloat4*)wv + (size_t)b * SS * D4 + col4;

    float4 s = make_float4(0.f, 0.f, 0.f, 0.f);
    float4 c = make_float4(0.f, 0.f, 0.f, 0.f);
    #pragma unroll 8
    for (int t = t0 + w; t < t1; t += 4) {
        nfloat4 v = __builtin_nontemporal_load(base + (size_t)t * D4);
        s.x += v.x; s.y += v.y; s.z += v.z; s.w += v.w;
        c.x += (v.x != 0.f) ? 1.f : 0.f;
        c.y += (v.y != 0.f) ? 1.f : 0.f;
        c.z += (v.z != 0.f) ? 1.f : 0.f;
        c.w += (v.w != 0.f) ? 1.f : 0.f;
    }

    __shared__ float4 s_s[4][64];
    __shared__ float4 s_c[4][64];
    s_s[w][lane] = s;
    s_c[w][lane] = c;
    __syncthreads();

    if (tid < 64) {
        float4 S = make_float4(0.f, 0.f, 0.f, 0.f);
        float4 C = make_float4(0.f, 0.f, 0.f, 0.f);
        #pragma unroll
        for (int j = 0; j < 4; ++j) {
            float4 a = s_s[j][tid], d = s_c[j][tid];
            S.x += a.x; S.y += a.y; S.z += a.z; S.w += a.w;
            C.x += d.x; C.y += d.y; C.z += d.z; C.w += d.w;
        }
        const size_t rec = (size_t)(b * MAXCH + cidx);
        ((float4*)ws_sum)[rec * D4 + g * 64 + tid] = S;
        uchar4 u;                      // chunk counts <= 128, exact in u8
        u.x = (unsigned char)C.x; u.y = (unsigned char)C.y;
        u.z = (unsigned char)C.z; u.w = (unsigned char)C.w;
        ((uchar4*)ws_cnt)[rec * D4 + g * 64 + tid] = u;
    }
}

// ---------------- Phase C: finalize (mean, fallback, rep, masks) -----------
// grid: BB*NN = 512 blocks, 256 threads (192 active cols). Gathers the
// segment's K chunk records, then proven epilogue.
__global__ __launch_bounds__(256) void finalize_kernel(
    const float* __restrict__ wv,
    const int* __restrict__ rep_ids,
    const float* __restrict__ rep_mask,
    const int* __restrict__ lens,
    const float* __restrict__ len_mask,
    const float* __restrict__ ws_sum,
    const unsigned char* __restrict__ ws_cnt,
    float* __restrict__ out)
{
    __shared__ float s_part[4];
    __shared__ int s_info[2];
    const int sgid = blockIdx.x;          // b*NN + n
    const int b = sgid >> 6, n = sgid & 63;
    const int tid = threadIdx.x;
    const int lane = tid & 63;

    if (tid < 64) {                       // wave 0: chunk-base scan
        const int l    = lens[b * NN + tid];
        const int nchl = (l + CHT - 1) >> 7;
        int inch = nchl;
        #pragma unroll
        for (int off = 1; off < 64; off <<= 1) {
            int a = __shfl_up(inch, off); if (lane >= off) inch += a;
        }
        if (tid == n) { s_info[0] = inch - nchl; s_info[1] = nchl; }
    }
    __syncthreads();
    const int ch_base = s_info[0];
    const int K       = s_info[1];
    const bool active = tid < D4;

    float4 S = make_float4(0,0,0,0), C = S;
    if (active) {
        for (int k = 0; k < K; ++k) {
            const size_t rec = (size_t)(b * MAXCH + ch_base + k);
            float4 sv = ((const float4*)ws_sum)[rec * D4 + tid];
            uchar4 cv = ((const uchar4*)ws_cnt)[rec * D4 + tid];
            S.x += sv.x; S.y += sv.y; S.z += sv.z; S.w += sv.w;
            C.x += (float)cv.x; C.y += (float)cv.y;
            C.z += (float)cv.z; C.w += (float)cv.w;
        }
    }

    float tot = C.x + C.y + C.z + C.w;    // 0 for inactive lanes
    #pragma unroll
    for (int off = 32; off; off >>= 1) tot += __shfl_xor(tot, off);
    if ((tid & 63) == 0) s_part[tid >> 6] = tot;
    __syncthreads();
    const float total = s_part[0] + s_part[1] + s_part[2] + s_part[3];

    if (active) {
        float4 mean;
        mean.x = S.x / fmaxf(C.x, 1.f);
        mean.y = S.y / fmaxf(C.y, 1.f);
        mean.z = S.z / fmaxf(C.z, 1.f);
        mean.w = S.w / fmaxf(C.w, 1.f);
        if (total == 0.f) mean = ((const float4*)wv)[tid];   // wv[0,0,:]

        const float lm = len_mask[sgid];
        mean.x *= lm; mean.y *= lm; mean.z *= lm; mean.w *= lm;

        float4* out4 = (float4*)out;
        out4[(size_t)(b * 2 * NN + NN + n) * D4 + tid] = mean;

        const int   rid = rep_ids[sgid];
        const float rm  = rep_mask[sgid];
        float4 rv = ((const float4*)wv)[(size_t)(b * SS + rid) * D4 + tid];
        rv.x *= rm; rv.y *= rm; rv.z *= rm; rv.w *= rm;
        out4[(size_t)(b * 2 * NN + n) * D4 + tid] = rv;

        if (tid == 0) {
            float* masks = out + (size_t)BB * 2 * NN * DD;
            masks[b * 2 * NN + n]      = rm;
            masks[b * 2 * NN + NN + n] = lm;
        }
    }
}

extern "C" void kernel_launch(void* const* d_in, const int* in_sizes, int n_in,
                              void* d_out, int out_size, void* d_ws, size_t ws_size,
                              hipStream_t stream) {
    const float* wv       = (const float*)d_in[0];
    const int*   rep_ids  = (const int*)d_in[1];
    const float* rep_mask = (const float*)d_in[2];
    const int*   lens     = (const int*)d_in[3];
    const float* len_mask = (const float*)d_in[4];
    float*       out      = (float*)d_out;
    float*         ws_sum = (float*)d_ws;
    unsigned char* ws_cnt = (unsigned char*)d_ws + (size_t)NREC * DD * 4;

    dim3 gridB(3 * MAXCH, BB);
    chunk_kernel<<<gridB, 256, 0, stream>>>(wv, lens, ws_sum, ws_cnt);
    finalize_kernel<<<BB * NN, 256, 0, stream>>>(wv, rep_ids, rep_mask, lens,
                                                 len_mask, ws_sum, ws_cnt, out);
}